// Round 12
// baseline (184.755 us; speedup 1.0000x reference)
//
#include <hip/hip_runtime.h>

#define NTOK 16384
#define DIM 256
#define NEXP 8
#define HID 512
#define CAP 5120      // per-expert slot capacity
#define CSTRIDE 16    // counts[e*CSTRIDE]: 64B apart
#define HC 32         // fused kernel h-chunk
#define A2S 40        // HB row stride in ushorts (80B = 5*16B: aligned b128, spread banks)

typedef unsigned short ushort_t;
typedef short bf16x8 __attribute__((ext_vector_type(8)));
typedef float f32x4 __attribute__((ext_vector_type(4)));

#define ASG __attribute__((address_space(1)))
#define ASL __attribute__((address_space(3)))

static __device__ __forceinline__ ushort_t f2bf(float f) {
    unsigned int u = __float_as_uint(f);
    unsigned int r = (u + 0x7FFFu + ((u >> 16) & 1u)) >> 16;
    return (ushort_t)r;
}
static __device__ __forceinline__ float bf2f(ushort_t u) {
    unsigned int x = ((unsigned int)u) << 16;
    return __uint_as_float(x);
}
// tanh-form GELU, exp2-folded + fast rcp: ~7 VALU ops, max |err| ~1e-3
static __device__ __forceinline__ float gelu_fast(float v) {
    float v2 = v * v;
    float u = v * __builtin_fmaf(v2, -0.1029407079f, -2.3022090196f);
    float e = __builtin_amdgcn_exp2f(u);
    return v * __builtin_amdgcn_rcpf(1.0f + e);
}
#define PIN(x) asm volatile("" : "+v"(x))

// ---------------- kernel T: transpose weights fp32->bf16, zero counts ----------------
__global__ void k_transpose(const float* __restrict__ w1, const float* __restrict__ w2,
                            ushort_t* __restrict__ w1t, ushort_t* __restrict__ w2t,
                            int* __restrict__ counts) {
    __shared__ ushort_t tile[64][72];
    if (blockIdx.x == 0 && threadIdx.x < NEXP * CSTRIDE) counts[threadIdx.x] = 0;
    int b = blockIdx.x;
    const float* src; ushort_t* dst; int R, C, e, t;
    if (b < 256) { e = b >> 5; t = b & 31; src = w1; dst = w1t + e * DIM * HID; R = DIM; C = HID; }
    else { b -= 256; e = b >> 5; t = b & 31; src = w2; dst = w2t + e * DIM * HID; R = HID; C = DIM; }
    size_t ebase = (size_t)e * DIM * HID;
    int tilesC = C >> 6;
    int rt = t / tilesC, ct = t % tilesC;
    for (int i = 0; i < 16; i++) {
        int flat = i * 256 + threadIdx.x;
        int lr = flat >> 6, lc = flat & 63;
        tile[lr][lc] = f2bf(src[ebase + (size_t)(rt * 64 + lr) * C + ct * 64 + lc]);
    }
    __syncthreads();
    for (int i = 0; i < 16; i++) {
        int flat = i * 256 + threadIdx.x;
        int lr = flat >> 6, lc = flat & 63;
        dst[(ct * 64 + lr) * R + rt * 64 + lc] = tile[lc][lr];
    }
}

// ---------------- kernel R: router + X->bf16 canonicalize (fused) ----------------
__global__ void k_router(const float* __restrict__ X, const float* __restrict__ Wg,
                         int* counts, int* tok_list, int* inv_idx, float* inv_w,
                         ushort_t* __restrict__ Xb) {
    __shared__ float xs[64][257];
    __shared__ float lg[64][8];
    __shared__ int te0[64], te1[64], lo0[64], lo1[64];
    __shared__ float tw0[64], tw1[64];
    __shared__ int lcnt[NEXP], gbase[NEXP];
    int tid = threadIdx.x;
    int tok0 = blockIdx.x * 64;
    if (tid < NEXP) lcnt[tid] = 0;
    for (int i = 0; i < 8; i++) {
        int flat = i * 256 + tid;
        int r = flat >> 5, c8 = (flat & 31) << 3;
        const float* row = X + (size_t)(tok0 + r) * DIM + c8;
        float4 a = *(const float4*)row;
        float4 b = *(const float4*)(row + 4);
        xs[r][c8 + 0] = a.x; xs[r][c8 + 1] = a.y; xs[r][c8 + 2] = a.z; xs[r][c8 + 3] = a.w;
        xs[r][c8 + 4] = b.x; xs[r][c8 + 5] = b.y; xs[r][c8 + 6] = b.z; xs[r][c8 + 7] = b.w;
    }
    __syncthreads();
    for (int i = 0; i < 8; i++) {
        int flat = i * 256 + tid;
        int r = flat >> 5, c8 = (flat & 31) << 3;
        ushort_t pk[8];
#pragma unroll
        for (int j = 0; j < 8; j++) pk[j] = f2bf(xs[r][c8 + j]);
        *(int4*)(Xb + (size_t)(tok0 + r) * DIM + c8) = *(const int4*)pk;
    }
    int tl = tid & 63, pair = tid >> 6;
    float l0 = 0.f, l1 = 0.f;
    for (int d = 0; d < DIM; d++) {
        float x = xs[tl][d];
        l0 += x * Wg[d * NEXP + 2 * pair];
        l1 += x * Wg[d * NEXP + 2 * pair + 1];
    }
    lg[tl][2 * pair] = l0; lg[tl][2 * pair + 1] = l1;
    __syncthreads();
    if (tid < 64) {
        float best = -1e30f; int bi = 0;
#pragma unroll
        for (int e = 0; e < NEXP; e++) { float v = lg[tid][e]; if (v > best) { best = v; bi = e; } }
        float best2 = -1e30f; int bi2 = 0;
#pragma unroll
        for (int e = 0; e < NEXP; e++) { if (e == bi) continue; float v = lg[tid][e]; if (v > best2) { best2 = v; bi2 = e; } }
        float ed = __expf(best2 - best);
        te0[tid] = bi; te1[tid] = bi2;
        tw0[tid] = 1.0f / (1.0f + ed);
        tw1[tid] = ed / (1.0f + ed);
        lo0[tid] = atomicAdd(&lcnt[bi], 1);
        lo1[tid] = atomicAdd(&lcnt[bi2], 1);
    }
    __syncthreads();
    if (tid < NEXP) gbase[tid] = atomicAdd(&counts[tid * CSTRIDE], lcnt[tid]);
    __syncthreads();
    if (tid < 64) {
        int token = tok0 + tid;
        int e0 = te0[tid], e1 = te1[tid];
        int p0 = gbase[e0] + lo0[tid]; if (p0 >= CAP) p0 = CAP - 1;
        int p1 = gbase[e1] + lo1[tid]; if (p1 >= CAP) p1 = CAP - 1;
        tok_list[e0 * CAP + p0] = token;
        tok_list[e1 * CAP + p1] = token;
        inv_idx[token * 2]     = (e0 << 16) | p0;  inv_w[token * 2]     = tw0[tid];
        inv_idx[token * 2 + 1] = (e1 << 16) | p1;  inv_w[token * 2 + 1] = tw1[tid];
    }
}

// ---------------- kernel M: FUSED GEMM1+GELU+GEMM2, tf=2 + gload_lds ping-pong ----------
// grid: e(8) x tile(40) of 128 tokens (active ~256 blocks ~ 1/CU). Block 256 thr/4 waves;
// wave = 32 tokens (2 x 16-frag): every weight ds_read_b128 feeds TWO MFMAs -> weight-LDS
// traffic per MFMA halves (fused kernel measured LDS-pipe-bound at tf=1).
// Staging: R11-verified global_load_lds ping-pong (register-free -> no spill at ~240 VGPR).
// __launch_bounds__(256,1): VGPR cap 512, guarantees no spill.
__launch_bounds__(256, 1)
__global__ void k_mlp_fused(const ushort_t* __restrict__ Xb,
                            const ushort_t* __restrict__ w1t, const float* __restrict__ b1,
                            const ushort_t* __restrict__ w2t, const float* __restrict__ b2,
                            const int* __restrict__ counts, const int* __restrict__ tok_list,
                            ushort_t* __restrict__ yb) {
    __shared__ ushort_t A1[2][HC * DIM];   // [32 h][256 d] linear, 2x16KB
    __shared__ ushort_t A2[2][DIM * HC];   // [256 d][32 h] linear, 2x16KB
    __shared__ ushort_t HB[128 * A2S];     // h bounce [128 tok][32 h], 10.25KB (wave-private)
    int b = blockIdx.x;
    int e = b / 40;
    int tile = b % 40;
    int count = counts[e * CSTRIDE];
    if (count > CAP) count = CAP;
    int t0 = tile * 128;
    if (t0 >= count) return;

    int tid = threadIdx.x;
    int w = tid >> 6, l = tid & 63, ln = l & 15, q = l >> 4;

    // two 16-token X fragment sets per wave (tf=2), K=256 in registers, loaded once
    int arow0 = t0 + 32 * w + ln;
    int arow1 = arow0 + 16;
    int ci0 = (arow0 < count) ? arow0 : (count - 1);
    int ci1 = (arow1 < count) ? arow1 : (count - 1);
    int tk0 = tok_list[e * CAP + ci0];
    int tk1 = tok_list[e * CAP + ci1];
    const ushort_t* xr0 = Xb + (size_t)tk0 * DIM;
    const ushort_t* xr1 = Xb + (size_t)tk1 * DIM;
    bf16x8 xf0[8], xf1[8];
#pragma unroll
    for (int ks = 0; ks < 8; ks++) {
        xf0[ks] = *(const bf16x8*)(xr0 + ks * 32 + q * 8);
        xf1[ks] = *(const bf16x8*)(xr1 + ks * 32 + q * 8);
    }
#pragma unroll
    for (int ks = 0; ks < 8; ks++) { PIN(xf0[ks]); PIN(xf1[ks]); }

    const ushort_t* w1te = w1t + (size_t)e * DIM * HID;
    const ushort_t* w2te = w2t + (size_t)e * DIM * HID;

    f32x4 zf = {0.f, 0.f, 0.f, 0.f};
    f32x4 yacc[16][2];                   // y[d = cf2*16+q*4+r][tok = ln+16t], 128 VGPR
#pragma unroll
    for (int i = 0; i < 16; i++) { yacc[i][0] = zf; yacc[i][1] = zf; }

    // DMA stage (R11-verified): LDS dest linear, source inverse-XOR-swizzled per lane.
#define STAGE(hcs, pb)                                                                   \
    {                                                                                    \
        _Pragma("unroll")                                                                \
        for (int i = 0; i < 4; i++) {                                                    \
            int g = w * 4 + i;                                                           \
            int r1_ = (g << 1) + (l >> 5);              /* A1 row 0..31 */               \
            int cb1_ = ((l & 31) << 4) ^ ((r1_ & 7) << 4);                               \
            const char* s1_ = (const char*)(w1te + (size_t)((hcs) + r1_) * DIM) + cb1_;  \
            __builtin_amdgcn_global_load_lds((ASG const void*)s1_,                       \
                (ASL void*)((char*)&A1[pb][0] + (g << 10)), 16, 0, 0);                   \
            int r2_ = (g << 4) + (l >> 2);              /* A2 row 0..255 */              \
            int cb2_ = ((l & 3) << 4) ^ ((r2_ & 3) << 4);                                \
            const char* s2_ = (const char*)(w2te + (size_t)r2_ * HID + (hcs)) + cb2_;    \
            __builtin_amdgcn_global_load_lds((ASG const void*)s2_,                       \
                (ASL void*)((char*)&A2[pb][0] + (g << 10)), 16, 0, 0);                   \
        }                                                                                \
    }

    STAGE(0, 0);
    __syncthreads();                      // drain: buf0 ready

    for (int ic = 0; ic < 16; ic++) {
        int hc = ic * HC;
        int p = ic & 1;
        if (ic < 15) STAGE(hc + HC, p ^ 1);   // fly under this chunk's compute

        // GEMM1: h[hc + cf*16+q*4+r][tok]; each weight read feeds both token frags
        f32x4 hacc[2][2];
        hacc[0][0] = zf; hacc[0][1] = zf; hacc[1][0] = zf; hacc[1][1] = zf;
#pragma unroll
        for (int ks = 0; ks < 8; ks++) {
#pragma unroll
            for (int cf = 0; cf < 2; cf++) {
                int row = cf * 16 + ln;
                bf16x8 wfr = *(const bf16x8*)(&A1[p][row * DIM + (((ks * 4 + q) ^ (row & 7)) << 3)]);
                hacc[cf][0] = __builtin_amdgcn_mfma_f32_16x16x32_bf16(wfr, xf0[ks], hacc[cf][0], 0, 0, 0);
                hacc[cf][1] = __builtin_amdgcn_mfma_f32_16x16x32_bf16(wfr, xf1[ks], hacc[cf][1], 0, 0, 0);
            }
        }
        // GELU + bounce h via wave-private LDS rows (wave w owns rows 32w..32w+31)
#pragma unroll
        for (int cf = 0; cf < 2; cf++) {
            float4 bv = *(const float4*)(b1 + e * HID + hc + cf * 16 + q * 4);
#pragma unroll
            for (int t = 0; t < 2; t++) {
                ushort4 pk;
                pk.x = f2bf(gelu_fast(hacc[cf][t][0] + bv.x));
                pk.y = f2bf(gelu_fast(hacc[cf][t][1] + bv.y));
                pk.z = f2bf(gelu_fast(hacc[cf][t][2] + bv.z));
                pk.w = f2bf(gelu_fast(hacc[cf][t][3] + bv.w));
                *(ushort4*)(HB + (32 * w + 16 * t + ln) * A2S + cf * 16 + q * 4) = pk;
            }
        }
        // GEMM2 partial: K-slice = this h-chunk; each weight read feeds both token frags
        bf16x8 hf0 = *(const bf16x8*)(HB + (32 * w + ln) * A2S + q * 8);
        bf16x8 hf1 = *(const bf16x8*)(HB + (32 * w + 16 + ln) * A2S + q * 8);
#pragma unroll
        for (int cf2 = 0; cf2 < 16; cf2++) {
            int row2 = cf2 * 16 + ln;
            bf16x8 wfr2 = *(const bf16x8*)(&A2[p][row2 * HC + ((q ^ (row2 & 3)) << 3)]);
            yacc[cf2][0] = __builtin_amdgcn_mfma_f32_16x16x32_bf16(wfr2, hf0, yacc[cf2][0], 0, 0, 0);
            yacc[cf2][1] = __builtin_amdgcn_mfma_f32_16x16x32_bf16(wfr2, hf1, yacc[cf2][1], 0, 0, 0);
        }
        __syncthreads();                 // rendezvous + vmcnt drain (DMA covered by compute)
    }
    // epilogue: y + b2 -> bf16 -> yb, two token rows per thread
    size_t yb0 = ((size_t)e * CAP + arow0) * DIM;
    size_t yb1 = ((size_t)e * CAP + arow1) * DIM;
#pragma unroll
    for (int cf2 = 0; cf2 < 16; cf2++) {
        float4 bv = *(const float4*)(b2 + e * DIM + cf2 * 16 + q * 4);
        ushort4 pk0, pk1;
        pk0.x = f2bf(yacc[cf2][0][0] + bv.x);
        pk0.y = f2bf(yacc[cf2][0][1] + bv.y);
        pk0.z = f2bf(yacc[cf2][0][2] + bv.z);
        pk0.w = f2bf(yacc[cf2][0][3] + bv.w);
        pk1.x = f2bf(yacc[cf2][1][0] + bv.x);
        pk1.y = f2bf(yacc[cf2][1][1] + bv.y);
        pk1.z = f2bf(yacc[cf2][1][2] + bv.z);
        pk1.w = f2bf(yacc[cf2][1][3] + bv.w);
        *(ushort4*)(yb + yb0 + cf2 * 16 + q * 4) = pk0;
        *(ushort4*)(yb + yb1 + cf2 * 16 + q * 4) = pk1;
    }
#undef STAGE
}

// ---------------- kernel F: combine y0*w0 + y1*w1 -> out (fp32) ----------------
__global__ void k_combine(const ushort_t* __restrict__ yb, const int* __restrict__ inv_idx,
                          const float* __restrict__ inv_w, float* __restrict__ out) {
    int tid = threadIdx.x;
    int n = blockIdx.x * 8 + (tid >> 5);
    int l32 = tid & 31, c8 = l32 << 3;
    int i0 = inv_idx[2 * n], i1 = inv_idx[2 * n + 1];
    float w0 = inv_w[2 * n], w1 = inv_w[2 * n + 1];
    size_t r0 = (size_t)(i0 >> 16) * CAP + (i0 & 0xFFFF);
    size_t r1 = (size_t)(i1 >> 16) * CAP + (i1 & 0xFFFF);
    int4 v0 = *(const int4*)(yb + r0 * DIM + c8);
    int4 v1 = *(const int4*)(yb + r1 * DIM + c8);
    ushort_t* p0 = (ushort_t*)&v0;
    ushort_t* p1 = (ushort_t*)&v1;
    float4 oa, ob;
    oa.x = w0 * bf2f(p0[0]) + w1 * bf2f(p1[0]);
    oa.y = w0 * bf2f(p0[1]) + w1 * bf2f(p1[1]);
    oa.z = w0 * bf2f(p0[2]) + w1 * bf2f(p1[2]);
    oa.w = w0 * bf2f(p0[3]) + w1 * bf2f(p1[3]);
    ob.x = w0 * bf2f(p0[4]) + w1 * bf2f(p1[4]);
    ob.y = w0 * bf2f(p0[5]) + w1 * bf2f(p1[5]);
    ob.z = w0 * bf2f(p0[6]) + w1 * bf2f(p1[6]);
    ob.w = w0 * bf2f(p0[7]) + w1 * bf2f(p1[7]);
    float4* op = (float4*)(out + (size_t)n * DIM + c8);
    op[0] = oa; op[1] = ob;
}

extern "C" void kernel_launch(void* const* d_in, const int* in_sizes, int n_in,
                              void* d_out, int out_size, void* d_ws, size_t ws_size,
                              hipStream_t stream) {
    const float* X  = (const float*)d_in[0];
    const float* Wg = (const float*)d_in[1];
    const float* w1 = (const float*)d_in[2];
    const float* b1 = (const float*)d_in[3];
    const float* w2 = (const float*)d_in[4];
    const float* b2 = (const float*)d_in[5];

    char* ws = (char*)d_ws;
    size_t off = 0;
    int* counts = (int*)(ws + off);        off = 1024;
    int* tok_list = (int*)(ws + off);      off += (size_t)NEXP * CAP * 4;        // 160KB
    int* inv_idx = (int*)(ws + off);       off += (size_t)NTOK * 2 * 4;          // 128KB
    float* inv_w = (float*)(ws + off);     off += (size_t)NTOK * 2 * 4;          // 128KB
    ushort_t* w1t = (ushort_t*)(ws + off); off += (size_t)NEXP * DIM * HID * 2;  // 2MB
    ushort_t* w2t = (ushort_t*)(ws + off); off += (size_t)NEXP * DIM * HID * 2;  // 2MB
    ushort_t* Xb = (ushort_t*)(ws + off);  off += (size_t)NTOK * DIM * 2;        // 8.4MB
    ushort_t* yb = (ushort_t*)(ws + off);  off += (size_t)NEXP * CAP * DIM * 2;  // 21MB

    k_transpose<<<512, 256, 0, stream>>>(w1, w2, w1t, w2t, counts);
    k_router<<<256, 256, 0, stream>>>(X, Wg, counts, tok_list, inv_idx, inv_w, Xb);
    k_mlp_fused<<<NEXP * 40, 256, 0, stream>>>(Xb, w1t, b1, w2t, b2, counts, tok_list, yb);
    k_combine<<<2048, 256, 0, stream>>>(yb, inv_idx, inv_w, (float*)d_out);
}

// Round 13
// 180.416 us; speedup vs baseline: 1.0240x; 1.0240x over previous
//
#include <hip/hip_runtime.h>

#define NTOK 16384
#define DIM 256
#define NEXP 8
#define HID 512
#define CAP 5120      // per-expert slot capacity
#define CSTRIDE 16    // counts[e*CSTRIDE]: 64B apart
#define HC 32         // fused kernel h-chunk
#define HBS 40        // HB row stride in ushorts (80B = 5*16B: aligned, bank-spread)

typedef unsigned short ushort_t;
typedef short bf16x8 __attribute__((ext_vector_type(8)));
typedef float f32x4 __attribute__((ext_vector_type(4)));

static __device__ __forceinline__ ushort_t f2bf(float f) {
    unsigned int u = __float_as_uint(f);
    unsigned int r = (u + 0x7FFFu + ((u >> 16) & 1u)) >> 16;
    return (ushort_t)r;
}
static __device__ __forceinline__ float bf2f(ushort_t u) {
    unsigned int x = ((unsigned int)u) << 16;
    return __uint_as_float(x);
}
// tanh-form GELU, exp2-folded + fast rcp: ~7 VALU ops, max |err| ~1e-3
static __device__ __forceinline__ float gelu_fast(float v) {
    float v2 = v * v;
    float u = v * __builtin_fmaf(v2, -0.1029407079f, -2.3022090196f);
    float e = __builtin_amdgcn_exp2f(u);
    return v * __builtin_amdgcn_rcpf(1.0f + e);
}
#define PIN(x) asm volatile("" : "+v"(x))

// ---------------- kernel T: transpose weights fp32->bf16, zero counts ----------------
__global__ void k_transpose(const float* __restrict__ w1, const float* __restrict__ w2,
                            ushort_t* __restrict__ w1t, ushort_t* __restrict__ w2t,
                            int* __restrict__ counts) {
    __shared__ ushort_t tile[64][72];
    if (blockIdx.x == 0 && threadIdx.x < NEXP * CSTRIDE) counts[threadIdx.x] = 0;
    int b = blockIdx.x;
    const float* src; ushort_t* dst; int R, C, e, t;
    if (b < 256) { e = b >> 5; t = b & 31; src = w1; dst = w1t + e * DIM * HID; R = DIM; C = HID; }
    else { b -= 256; e = b >> 5; t = b & 31; src = w2; dst = w2t + e * DIM * HID; R = HID; C = DIM; }
    size_t ebase = (size_t)e * DIM * HID;
    int tilesC = C >> 6;
    int rt = t / tilesC, ct = t % tilesC;
    for (int i = 0; i < 16; i++) {
        int flat = i * 256 + threadIdx.x;
        int lr = flat >> 6, lc = flat & 63;
        tile[lr][lc] = f2bf(src[ebase + (size_t)(rt * 64 + lr) * C + ct * 64 + lc]);
    }
    __syncthreads();
    for (int i = 0; i < 16; i++) {
        int flat = i * 256 + threadIdx.x;
        int lr = flat >> 6, lc = flat & 63;
        dst[(ct * 64 + lr) * R + rt * 64 + lc] = tile[lc][lr];
    }
}

// ---------------- kernel R: router + X->bf16 canonicalize (fused) ----------------
__global__ void k_router(const float* __restrict__ X, const float* __restrict__ Wg,
                         int* counts, int* tok_list, int* inv_idx, float* inv_w,
                         ushort_t* __restrict__ Xb) {
    __shared__ float xs[64][257];
    __shared__ float lg[64][8];
    __shared__ int te0[64], te1[64], lo0[64], lo1[64];
    __shared__ float tw0[64], tw1[64];
    __shared__ int lcnt[NEXP], gbase[NEXP];
    int tid = threadIdx.x;
    int tok0 = blockIdx.x * 64;
    if (tid < NEXP) lcnt[tid] = 0;
    for (int i = 0; i < 8; i++) {
        int flat = i * 256 + tid;
        int r = flat >> 5, c8 = (flat & 31) << 3;
        const float* row = X + (size_t)(tok0 + r) * DIM + c8;
        float4 a = *(const float4*)row;
        float4 b = *(const float4*)(row + 4);
        xs[r][c8 + 0] = a.x; xs[r][c8 + 1] = a.y; xs[r][c8 + 2] = a.z; xs[r][c8 + 3] = a.w;
        xs[r][c8 + 4] = b.x; xs[r][c8 + 5] = b.y; xs[r][c8 + 6] = b.z; xs[r][c8 + 7] = b.w;
    }
    __syncthreads();
    for (int i = 0; i < 8; i++) {
        int flat = i * 256 + tid;
        int r = flat >> 5, c8 = (flat & 31) << 3;
        ushort_t pk[8];
#pragma unroll
        for (int j = 0; j < 8; j++) pk[j] = f2bf(xs[r][c8 + j]);
        *(int4*)(Xb + (size_t)(tok0 + r) * DIM + c8) = *(const int4*)pk;
    }
    int tl = tid & 63, pair = tid >> 6;
    float l0 = 0.f, l1 = 0.f;
    for (int d = 0; d < DIM; d++) {
        float x = xs[tl][d];
        l0 += x * Wg[d * NEXP + 2 * pair];
        l1 += x * Wg[d * NEXP + 2 * pair + 1];
    }
    lg[tl][2 * pair] = l0; lg[tl][2 * pair + 1] = l1;
    __syncthreads();
    if (tid < 64) {
        float best = -1e30f; int bi = 0;
#pragma unroll
        for (int e = 0; e < NEXP; e++) { float v = lg[tid][e]; if (v > best) { best = v; bi = e; } }
        float best2 = -1e30f; int bi2 = 0;
#pragma unroll
        for (int e = 0; e < NEXP; e++) { if (e == bi) continue; float v = lg[tid][e]; if (v > best2) { best2 = v; bi2 = e; } }
        float ed = __expf(best2 - best);
        te0[tid] = bi; te1[tid] = bi2;
        tw0[tid] = 1.0f / (1.0f + ed);
        tw1[tid] = ed / (1.0f + ed);
        lo0[tid] = atomicAdd(&lcnt[bi], 1);
        lo1[tid] = atomicAdd(&lcnt[bi2], 1);
    }
    __syncthreads();
    if (tid < NEXP) gbase[tid] = atomicAdd(&counts[tid * CSTRIDE], lcnt[tid]);
    __syncthreads();
    if (tid < 64) {
        int token = tok0 + tid;
        int e0 = te0[tid], e1 = te1[tid];
        int p0 = gbase[e0] + lo0[tid]; if (p0 >= CAP) p0 = CAP - 1;
        int p1 = gbase[e1] + lo1[tid]; if (p1 >= CAP) p1 = CAP - 1;
        tok_list[e0 * CAP + p0] = token;
        tok_list[e1 * CAP + p1] = token;
        inv_idx[token * 2]     = (e0 << 16) | p0;  inv_w[token * 2]     = tw0[tid];
        inv_idx[token * 2 + 1] = (e1 << 16) | p1;  inv_w[token * 2 + 1] = tw1[tid];
    }
}

// ---------------- kernel M: FUSED GEMM1+GELU+GEMM2 -> yb (R8 structure, slim LDS) -------
// grid: e(8) x tile(80) of 64 tokens, e-major. Block 256 thr / 4 waves; wave = 16 tokens.
// Identical to the verified 56us R8 kernel EXCEPT: A2 padded(40) -> linear(32) with XOR
// granule swizzle (write granule = g ^ (row&3); read granule = q ^ (row&3)) -> LDS
// 41.9 -> 37.5KB -> 4 blocks/CU (occupancy curve: 1->99.8us, 2->62.5, 3->56.0).
// Bank check: read slot (4*ln + q^(ln&3)) mod 8 is exactly uniform (8 lanes/slot = b128
// floor); write side likewise. Conflict-neutral, -4KB.
__launch_bounds__(256, 4)
__global__ void k_mlp_fused(const ushort_t* __restrict__ Xb,
                            const ushort_t* __restrict__ w1t, const float* __restrict__ b1,
                            const ushort_t* __restrict__ w2t, const float* __restrict__ b2,
                            const int* __restrict__ counts, const int* __restrict__ tok_list,
                            ushort_t* __restrict__ yb) {
    __shared__ ushort_t A1[HC * 264];    // w1 chunk [32 h][256 d] padded  16.9KB
    __shared__ ushort_t A2[DIM * HC];    // w2 chunk [256 d][32 h] linear+swz  16KB
    __shared__ ushort_t HB[64 * HBS];    // h bounce [64 tok][32 h]  5KB (wave-private rows)
    int b = blockIdx.x;
    int e = b / 80;
    int tile = b % 80;
    int count = counts[e * CSTRIDE];
    if (count > CAP) count = CAP;
    int t0 = tile * 64;
    if (t0 >= count) return;

    int tid = threadIdx.x;
    int w = tid >> 6, l = tid & 63, ln = l & 15, q = l >> 4;

    // X fragments (B-operand): 16 token rows per wave, K=256 in registers, loaded once
    int arow = t0 + 16 * w + ln;
    int ci = (arow < count) ? arow : (count - 1);
    int atok = tok_list[e * CAP + ci];
    const ushort_t* xrow = Xb + (size_t)atok * DIM;
    bf16x8 xf[8];
#pragma unroll
    for (int ks = 0; ks < 8; ks++)
        xf[ks] = *(const bf16x8*)(xrow + ks * 32 + q * 8);
#pragma unroll
    for (int ks = 0; ks < 8; ks++) PIN(xf[ks]);

    const ushort_t* w1te = w1t + (size_t)e * DIM * HID;
    const ushort_t* w2te = w2t + (size_t)e * DIM * HID;

    f32x4 zf = {0.f, 0.f, 0.f, 0.f};
    f32x4 yacc[16];                      // y[d = cf2*16+q*4+r][tok = ln], 64 VGPR
#pragma unroll
    for (int i = 0; i < 16; i++) yacc[i] = zf;

    for (int ic = 0; ic < 16; ic++) {
        int hc = ic * HC;
        __syncthreads();                 // previous chunk's A1/A2 reads complete
        // stage w1 chunk: 32 h-rows x 256 d = 1024 int4, 4/thread (32 int4 per row)
#pragma unroll
        for (int i = 0; i < 4; i++) {
            int flat = i * 256 + tid;
            int hr = flat >> 5, c8 = (flat & 31) << 3;
            *(int4*)(A1 + hr * 264 + c8) = *(const int4*)(w1te + (size_t)(hc + hr) * DIM + c8);
        }
        // stage w2 chunk: 256 d-rows x 32 h = 1024 int4, 4/thread; XOR-swizzled granule
#pragma unroll
        for (int i = 0; i < 4; i++) {
            int flat = i * 256 + tid;
            int dr = flat >> 2, g = flat & 3;
            *(int4*)(A2 + dr * HC + ((g ^ (dr & 3)) << 3)) =
                *(const int4*)(w2te + (size_t)dr * HID + hc + (g << 3));
        }
        __syncthreads();                 // staging visible

        // GEMM1: h-chunk acc, h[hc + cf*16+q*4+r][tok ln]
        f32x4 hacc[2];
        hacc[0] = zf; hacc[1] = zf;
#pragma unroll
        for (int ks = 0; ks < 8; ks++) {
            bf16x8 xk = xf[ks];
#pragma unroll
            for (int cf = 0; cf < 2; cf++) {
                bf16x8 wfr = *(const bf16x8*)(A1 + (cf * 16 + ln) * 264 + ks * 32 + q * 8);
                hacc[cf] = __builtin_amdgcn_mfma_f32_16x16x32_bf16(wfr, xk, hacc[cf], 0, 0, 0);
            }
        }
        // GELU + bounce h through wave-private LDS rows (no barrier: rows 16w..16w+15
        // written/read only by wave w; in-wave DS ops in-order + compiler lgkmcnt RAW)
#pragma unroll
        for (int cf = 0; cf < 2; cf++) {
            float4 bv = *(const float4*)(b1 + e * HID + hc + cf * 16 + q * 4);
            ushort4 pk;
            pk.x = f2bf(gelu_fast(hacc[cf][0] + bv.x));
            pk.y = f2bf(gelu_fast(hacc[cf][1] + bv.y));
            pk.z = f2bf(gelu_fast(hacc[cf][2] + bv.z));
            pk.w = f2bf(gelu_fast(hacc[cf][3] + bv.w));
            *(ushort4*)(HB + (16 * w + ln) * HBS + cf * 16 + q * 4) = pk;
        }
        // GEMM2 partial: K-slice = this h-chunk (32); h frag from own token row;
        // A2 read with matching XOR swizzle
        bf16x8 hf = *(const bf16x8*)(HB + (16 * w + ln) * HBS + q * 8);
#pragma unroll
        for (int cf2 = 0; cf2 < 16; cf2++) {
            int row2 = cf2 * 16 + ln;
            bf16x8 wfr2 = *(const bf16x8*)(A2 + row2 * HC + ((q ^ (row2 & 3)) << 3));
            yacc[cf2] = __builtin_amdgcn_mfma_f32_16x16x32_bf16(wfr2, hf, yacc[cf2], 0, 0, 0);
        }
    }
    // epilogue: y + b2 -> bf16 -> yb row
    size_t yrowbase = ((size_t)e * CAP + arow) * DIM;
#pragma unroll
    for (int cf2 = 0; cf2 < 16; cf2++) {
        float4 bv = *(const float4*)(b2 + e * DIM + cf2 * 16 + q * 4);
        ushort4 pk;
        pk.x = f2bf(yacc[cf2][0] + bv.x);
        pk.y = f2bf(yacc[cf2][1] + bv.y);
        pk.z = f2bf(yacc[cf2][2] + bv.z);
        pk.w = f2bf(yacc[cf2][3] + bv.w);
        *(ushort4*)(yb + yrowbase + cf2 * 16 + q * 4) = pk;
    }
}

// ---------------- kernel F: combine y0*w0 + y1*w1 -> out (fp32) ----------------
__global__ void k_combine(const ushort_t* __restrict__ yb, const int* __restrict__ inv_idx,
                          const float* __restrict__ inv_w, float* __restrict__ out) {
    int tid = threadIdx.x;
    int n = blockIdx.x * 8 + (tid >> 5);
    int l32 = tid & 31, c8 = l32 << 3;
    int i0 = inv_idx[2 * n], i1 = inv_idx[2 * n + 1];
    float w0 = inv_w[2 * n], w1 = inv_w[2 * n + 1];
    size_t r0 = (size_t)(i0 >> 16) * CAP + (i0 & 0xFFFF);
    size_t r1 = (size_t)(i1 >> 16) * CAP + (i1 & 0xFFFF);
    int4 v0 = *(const int4*)(yb + r0 * DIM + c8);
    int4 v1 = *(const int4*)(yb + r1 * DIM + c8);
    ushort_t* p0 = (ushort_t*)&v0;
    ushort_t* p1 = (ushort_t*)&v1;
    float4 oa, ob;
    oa.x = w0 * bf2f(p0[0]) + w1 * bf2f(p1[0]);
    oa.y = w0 * bf2f(p0[1]) + w1 * bf2f(p1[1]);
    oa.z = w0 * bf2f(p0[2]) + w1 * bf2f(p1[2]);
    oa.w = w0 * bf2f(p0[3]) + w1 * bf2f(p1[3]);
    ob.x = w0 * bf2f(p0[4]) + w1 * bf2f(p1[4]);
    ob.y = w0 * bf2f(p0[5]) + w1 * bf2f(p1[5]);
    ob.z = w0 * bf2f(p0[6]) + w1 * bf2f(p1[6]);
    ob.w = w0 * bf2f(p0[7]) + w1 * bf2f(p1[7]);
    float4* op = (float4*)(out + (size_t)n * DIM + c8);
    op[0] = oa; op[1] = ob;
}

extern "C" void kernel_launch(void* const* d_in, const int* in_sizes, int n_in,
                              void* d_out, int out_size, void* d_ws, size_t ws_size,
                              hipStream_t stream) {
    const float* X  = (const float*)d_in[0];
    const float* Wg = (const float*)d_in[1];
    const float* w1 = (const float*)d_in[2];
    const float* b1 = (const float*)d_in[3];
    const float* w2 = (const float*)d_in[4];
    const float* b2 = (const float*)d_in[5];

    char* ws = (char*)d_ws;
    size_t off = 0;
    int* counts = (int*)(ws + off);        off = 1024;
    int* tok_list = (int*)(ws + off);      off += (size_t)NEXP * CAP * 4;        // 160KB
    int* inv_idx = (int*)(ws + off);       off += (size_t)NTOK * 2 * 4;          // 128KB
    float* inv_w = (float*)(ws + off);     off += (size_t)NTOK * 2 * 4;          // 128KB
    ushort_t* w1t = (ushort_t*)(ws + off); off += (size_t)NEXP * DIM * HID * 2;  // 2MB
    ushort_t* w2t = (ushort_t*)(ws + off); off += (size_t)NEXP * DIM * HID * 2;  // 2MB
    ushort_t* Xb = (ushort_t*)(ws + off);  off += (size_t)NTOK * DIM * 2;        // 8.4MB
    ushort_t* yb = (ushort_t*)(ws + off);  off += (size_t)NEXP * CAP * DIM * 2;  // 21MB

    k_transpose<<<512, 256, 0, stream>>>(w1, w2, w1t, w2t, counts);
    k_router<<<256, 256, 0, stream>>>(X, Wg, counts, tok_list, inv_idx, inv_w, Xb);
    k_mlp_fused<<<NEXP * 80, 256, 0, stream>>>(Xb, w1t, b1, w2t, b2, counts, tok_list, yb);
    k_combine<<<2048, 256, 0, stream>>>(yb, inv_idx, inv_w, (float*)d_out);
}

// Round 15
// 154.040 us; speedup vs baseline: 1.1994x; 1.1712x over previous
//
#include <hip/hip_runtime.h>

#define NTOK 16384
#define DIM 256
#define NEXP 8
#define HID 512
#define CAP 5120      // per-expert slot capacity
#define CSTRIDE 16    // counts[e*CSTRIDE]: 64B apart
#define HC 32         // fused kernel h-chunk
#define HBS 40        // HB row stride in ushorts (80B = 5*16B: aligned, bank-spread)

typedef unsigned short ushort_t;
typedef short bf16x8 __attribute__((ext_vector_type(8)));
typedef float f32x4 __attribute__((ext_vector_type(4)));

static __device__ __forceinline__ ushort_t f2bf(float f) {
    unsigned int u = __float_as_uint(f);
    unsigned int r = (u + 0x7FFFu + ((u >> 16) & 1u)) >> 16;
    return (ushort_t)r;
}
static __device__ __forceinline__ float bf2f(ushort_t u) {
    unsigned int x = ((unsigned int)u) << 16;
    return __uint_as_float(x);
}
// tanh-form GELU, exp2-folded + fast rcp: ~7 VALU ops, max |err| ~1e-3
static __device__ __forceinline__ float gelu_fast(float v) {
    float v2 = v * v;
    float u = v * __builtin_fmaf(v2, -0.1029407079f, -2.3022090196f);
    float e = __builtin_amdgcn_exp2f(u);
    return v * __builtin_amdgcn_rcpf(1.0f + e);
}
#define PIN(x) asm volatile("" : "+v"(x))

// ---------------- kernel T: transpose weights fp32->bf16, zero counts ----------------
__global__ void k_transpose(const float* __restrict__ w1, const float* __restrict__ w2,
                            ushort_t* __restrict__ w1t, ushort_t* __restrict__ w2t,
                            int* __restrict__ counts) {
    __shared__ ushort_t tile[64][72];
    if (blockIdx.x == 0 && threadIdx.x < NEXP * CSTRIDE) counts[threadIdx.x] = 0;
    int b = blockIdx.x;
    const float* src; ushort_t* dst; int R, C, e, t;
    if (b < 256) { e = b >> 5; t = b & 31; src = w1; dst = w1t + e * DIM * HID; R = DIM; C = HID; }
    else { b -= 256; e = b >> 5; t = b & 31; src = w2; dst = w2t + e * DIM * HID; R = HID; C = DIM; }
    size_t ebase = (size_t)e * DIM * HID;
    int tilesC = C >> 6;
    int rt = t / tilesC, ct = t % tilesC;
    for (int i = 0; i < 16; i++) {
        int flat = i * 256 + threadIdx.x;
        int lr = flat >> 6, lc = flat & 63;
        tile[lr][lc] = f2bf(src[ebase + (size_t)(rt * 64 + lr) * C + ct * 64 + lc]);
    }
    __syncthreads();
    for (int i = 0; i < 16; i++) {
        int flat = i * 256 + threadIdx.x;
        int lr = flat >> 6, lc = flat & 63;
        dst[(ct * 64 + lr) * R + rt * 64 + lc] = tile[lc][lr];
    }
}

// ---------------- kernel R: router + X->bf16 canonicalize (fused) ----------------
__global__ void k_router(const float* __restrict__ X, const float* __restrict__ Wg,
                         int* counts, int* tok_list, int* inv_idx, float* inv_w,
                         ushort_t* __restrict__ Xb) {
    __shared__ float xs[64][257];
    __shared__ float lg[64][8];
    __shared__ int te0[64], te1[64], lo0[64], lo1[64];
    __shared__ float tw0[64], tw1[64];
    __shared__ int lcnt[NEXP], gbase[NEXP];
    int tid = threadIdx.x;
    int tok0 = blockIdx.x * 64;
    if (tid < NEXP) lcnt[tid] = 0;
    for (int i = 0; i < 8; i++) {
        int flat = i * 256 + tid;
        int r = flat >> 5, c8 = (flat & 31) << 3;
        const float* row = X + (size_t)(tok0 + r) * DIM + c8;
        float4 a = *(const float4*)row;
        float4 b = *(const float4*)(row + 4);
        xs[r][c8 + 0] = a.x; xs[r][c8 + 1] = a.y; xs[r][c8 + 2] = a.z; xs[r][c8 + 3] = a.w;
        xs[r][c8 + 4] = b.x; xs[r][c8 + 5] = b.y; xs[r][c8 + 6] = b.z; xs[r][c8 + 7] = b.w;
    }
    __syncthreads();
    for (int i = 0; i < 8; i++) {
        int flat = i * 256 + tid;
        int r = flat >> 5, c8 = (flat & 31) << 3;
        ushort_t pk[8];
#pragma unroll
        for (int j = 0; j < 8; j++) pk[j] = f2bf(xs[r][c8 + j]);
        *(int4*)(Xb + (size_t)(tok0 + r) * DIM + c8) = *(const int4*)pk;
    }
    int tl = tid & 63, pair = tid >> 6;
    float l0 = 0.f, l1 = 0.f;
    for (int d = 0; d < DIM; d++) {
        float x = xs[tl][d];
        l0 += x * Wg[d * NEXP + 2 * pair];
        l1 += x * Wg[d * NEXP + 2 * pair + 1];
    }
    lg[tl][2 * pair] = l0; lg[tl][2 * pair + 1] = l1;
    __syncthreads();
    if (tid < 64) {
        float best = -1e30f; int bi = 0;
#pragma unroll
        for (int e = 0; e < NEXP; e++) { float v = lg[tid][e]; if (v > best) { best = v; bi = e; } }
        float best2 = -1e30f; int bi2 = 0;
#pragma unroll
        for (int e = 0; e < NEXP; e++) { if (e == bi) continue; float v = lg[tid][e]; if (v > best2) { best2 = v; bi2 = e; } }
        float ed = __expf(best2 - best);
        te0[tid] = bi; te1[tid] = bi2;
        tw0[tid] = 1.0f / (1.0f + ed);
        tw1[tid] = ed / (1.0f + ed);
        lo0[tid] = atomicAdd(&lcnt[bi], 1);
        lo1[tid] = atomicAdd(&lcnt[bi2], 1);
    }
    __syncthreads();
    if (tid < NEXP) gbase[tid] = atomicAdd(&counts[tid * CSTRIDE], lcnt[tid]);
    __syncthreads();
    if (tid < 64) {
        int token = tok0 + tid;
        int e0 = te0[tid], e1 = te1[tid];
        int p0 = gbase[e0] + lo0[tid]; if (p0 >= CAP) p0 = CAP - 1;
        int p1 = gbase[e1] + lo1[tid]; if (p1 >= CAP) p1 = CAP - 1;
        tok_list[e0 * CAP + p0] = token;
        tok_list[e1 * CAP + p1] = token;
        inv_idx[token * 2]     = (e0 << 16) | p0;  inv_w[token * 2]     = tw0[tid];
        inv_idx[token * 2 + 1] = (e1 << 16) | p1;  inv_w[token * 2 + 1] = tw1[tid];
    }
}

// ---------------- kernel M: FUSED GEMM1+GELU+GEMM2 -> yb (R13 LDS diet, R8 reg budget) --
// grid: e(8) x tile(80) of 64 tokens, e-major. Block 256 thr / 4 waves; wave = 16 tokens.
// LDS 37.5KB -> 4 blocks/CU (occupancy curve: 1->99.8us, 2->62.5, 3->56.0, 4->this).
// __launch_bounds__(256,3): min-waves floor of 3 keeps the VGPR cap at 168 so the
// compiler returns to R8's ~84-VGPR no-spill allocation. R13's (256,4) capped VGPR at
// 128 -> xf spilled to scratch (VGPR 64, WRITE_SIZE +9.3MB, 78us). Occupancy comes from
// LDS (4 blocks), NOT the launch_bounds floor.
__launch_bounds__(256, 3)
__global__ void k_mlp_fused(const ushort_t* __restrict__ Xb,
                            const ushort_t* __restrict__ w1t, const float* __restrict__ b1,
                            const ushort_t* __restrict__ w2t, const float* __restrict__ b2,
                            const int* __restrict__ counts, const int* __restrict__ tok_list,
                            ushort_t* __restrict__ yb) {
    __shared__ ushort_t A1[HC * 264];    // w1 chunk [32 h][256 d] padded  16.9KB
    __shared__ ushort_t A2[DIM * HC];    // w2 chunk [256 d][32 h] linear+swz  16KB
    __shared__ ushort_t HB[64 * HBS];    // h bounce [64 tok][32 h]  5KB (wave-private rows)
    int b = blockIdx.x;
    int e = b / 80;
    int tile = b % 80;
    int count = counts[e * CSTRIDE];
    if (count > CAP) count = CAP;
    int t0 = tile * 64;
    if (t0 >= count) return;

    int tid = threadIdx.x;
    int w = tid >> 6, l = tid & 63, ln = l & 15, q = l >> 4;

    // X fragments (B-operand): 16 token rows per wave, K=256 in registers, loaded once
    int arow = t0 + 16 * w + ln;
    int ci = (arow < count) ? arow : (count - 1);
    int atok = tok_list[e * CAP + ci];
    const ushort_t* xrow = Xb + (size_t)atok * DIM;
    bf16x8 xf[8];
#pragma unroll
    for (int ks = 0; ks < 8; ks++)
        xf[ks] = *(const bf16x8*)(xrow + ks * 32 + q * 8);
#pragma unroll
    for (int ks = 0; ks < 8; ks++) PIN(xf[ks]);

    const ushort_t* w1te = w1t + (size_t)e * DIM * HID;
    const ushort_t* w2te = w2t + (size_t)e * DIM * HID;

    f32x4 zf = {0.f, 0.f, 0.f, 0.f};
    f32x4 yacc[16];                      // y[d = cf2*16+q*4+r][tok = ln], 64 VGPR
#pragma unroll
    for (int i = 0; i < 16; i++) yacc[i] = zf;

    for (int ic = 0; ic < 16; ic++) {
        int hc = ic * HC;
        __syncthreads();                 // previous chunk's A1/A2 reads complete
        // stage w1 chunk: 32 h-rows x 256 d = 1024 int4, 4/thread (32 int4 per row)
#pragma unroll
        for (int i = 0; i < 4; i++) {
            int flat = i * 256 + tid;
            int hr = flat >> 5, c8 = (flat & 31) << 3;
            *(int4*)(A1 + hr * 264 + c8) = *(const int4*)(w1te + (size_t)(hc + hr) * DIM + c8);
        }
        // stage w2 chunk: 256 d-rows x 32 h = 1024 int4, 4/thread; XOR-swizzled granule
#pragma unroll
        for (int i = 0; i < 4; i++) {
            int flat = i * 256 + tid;
            int dr = flat >> 2, g = flat & 3;
            *(int4*)(A2 + dr * HC + ((g ^ (dr & 3)) << 3)) =
                *(const int4*)(w2te + (size_t)dr * HID + hc + (g << 3));
        }
        __syncthreads();                 // staging visible

        // GEMM1: h-chunk acc, h[hc + cf*16+q*4+r][tok ln]
        f32x4 hacc[2];
        hacc[0] = zf; hacc[1] = zf;
#pragma unroll
        for (int ks = 0; ks < 8; ks++) {
            bf16x8 xk = xf[ks];
#pragma unroll
            for (int cf = 0; cf < 2; cf++) {
                bf16x8 wfr = *(const bf16x8*)(A1 + (cf * 16 + ln) * 264 + ks * 32 + q * 8);
                hacc[cf] = __builtin_amdgcn_mfma_f32_16x16x32_bf16(wfr, xk, hacc[cf], 0, 0, 0);
            }
        }
        // GELU + bounce h through wave-private LDS rows (no barrier: rows 16w..16w+15
        // written/read only by wave w; in-wave DS ops in-order + compiler lgkmcnt RAW)
#pragma unroll
        for (int cf = 0; cf < 2; cf++) {
            float4 bv = *(const float4*)(b1 + e * HID + hc + cf * 16 + q * 4);
            ushort4 pk;
            pk.x = f2bf(gelu_fast(hacc[cf][0] + bv.x));
            pk.y = f2bf(gelu_fast(hacc[cf][1] + bv.y));
            pk.z = f2bf(gelu_fast(hacc[cf][2] + bv.z));
            pk.w = f2bf(gelu_fast(hacc[cf][3] + bv.w));
            *(ushort4*)(HB + (16 * w + ln) * HBS + cf * 16 + q * 4) = pk;
        }
        // GEMM2 partial: K-slice = this h-chunk (32); h frag from own token row;
        // A2 read with matching XOR swizzle
        bf16x8 hf = *(const bf16x8*)(HB + (16 * w + ln) * HBS + q * 8);
#pragma unroll
        for (int cf2 = 0; cf2 < 16; cf2++) {
            int row2 = cf2 * 16 + ln;
            bf16x8 wfr2 = *(const bf16x8*)(A2 + row2 * HC + ((q ^ (row2 & 3)) << 3));
            yacc[cf2] = __builtin_amdgcn_mfma_f32_16x16x32_bf16(wfr2, hf, yacc[cf2], 0, 0, 0);
        }
    }
    // epilogue: y + b2 -> bf16 -> yb row
    size_t yrowbase = ((size_t)e * CAP + arow) * DIM;
#pragma unroll
    for (int cf2 = 0; cf2 < 16; cf2++) {
        float4 bv = *(const float4*)(b2 + e * DIM + cf2 * 16 + q * 4);
        ushort4 pk;
        pk.x = f2bf(yacc[cf2][0] + bv.x);
        pk.y = f2bf(yacc[cf2][1] + bv.y);
        pk.z = f2bf(yacc[cf2][2] + bv.z);
        pk.w = f2bf(yacc[cf2][3] + bv.w);
        *(ushort4*)(yb + yrowbase + cf2 * 16 + q * 4) = pk;
    }
}

// ---------------- kernel F: combine y0*w0 + y1*w1 -> out (fp32) ----------------
__global__ void k_combine(const ushort_t* __restrict__ yb, const int* __restrict__ inv_idx,
                          const float* __restrict__ inv_w, float* __restrict__ out) {
    int tid = threadIdx.x;
    int n = blockIdx.x * 8 + (tid >> 5);
    int l32 = tid & 31, c8 = l32 << 3;
    int i0 = inv_idx[2 * n], i1 = inv_idx[2 * n + 1];
    float w0 = inv_w[2 * n], w1 = inv_w[2 * n + 1];
    size_t r0 = (size_t)(i0 >> 16) * CAP + (i0 & 0xFFFF);
    size_t r1 = (size_t)(i1 >> 16) * CAP + (i1 & 0xFFFF);
    int4 v0 = *(const int4*)(yb + r0 * DIM + c8);
    int4 v1 = *(const int4*)(yb + r1 * DIM + c8);
    ushort_t* p0 = (ushort_t*)&v0;
    ushort_t* p1 = (ushort_t*)&v1;
    float4 oa, ob;
    oa.x = w0 * bf2f(p0[0]) + w1 * bf2f(p1[0]);
    oa.y = w0 * bf2f(p0[1]) + w1 * bf2f(p1[1]);
    oa.z = w0 * bf2f(p0[2]) + w1 * bf2f(p1[2]);
    oa.w = w0 * bf2f(p0[3]) + w1 * bf2f(p1[3]);
    ob.x = w0 * bf2f(p0[4]) + w1 * bf2f(p1[4]);
    ob.y = w0 * bf2f(p0[5]) + w1 * bf2f(p1[5]);
    ob.z = w0 * bf2f(p0[6]) + w1 * bf2f(p1[6]);
    ob.w = w0 * bf2f(p0[7]) + w1 * bf2f(p1[7]);
    float4* op = (float4*)(out + (size_t)n * DIM + c8);
    op[0] = oa; op[1] = ob;
}

extern "C" void kernel_launch(void* const* d_in, const int* in_sizes, int n_in,
                              void* d_out, int out_size, void* d_ws, size_t ws_size,
                              hipStream_t stream) {
    const float* X  = (const float*)d_in[0];
    const float* Wg = (const float*)d_in[1];
    const float* w1 = (const float*)d_in[2];
    const float* b1 = (const float*)d_in[3];
    const float* w2 = (const float*)d_in[4];
    const float* b2 = (const float*)d_in[5];

    char* ws = (char*)d_ws;
    size_t off = 0;
    int* counts = (int*)(ws + off);        off = 1024;
    int* tok_list = (int*)(ws + off);      off += (size_t)NEXP * CAP * 4;        // 160KB
    int* inv_idx = (int*)(ws + off);       off += (size_t)NTOK * 2 * 4;          // 128KB
    float* inv_w = (float*)(ws + off);     off += (size_t)NTOK * 2 * 4;          // 128KB
    ushort_t* w1t = (ushort_t*)(ws + off); off += (size_t)NEXP * DIM * HID * 2;  // 2MB
    ushort_t* w2t = (ushort_t*)(ws + off); off += (size_t)NEXP * DIM * HID * 2;  // 2MB
    ushort_t* Xb = (ushort_t*)(ws + off);  off += (size_t)NTOK * DIM * 2;        // 8.4MB
    ushort_t* yb = (ushort_t*)(ws + off);  off += (size_t)NEXP * CAP * DIM * 2;  // 21MB

    k_transpose<<<512, 256, 0, stream>>>(w1, w2, w1t, w2t, counts);
    k_router<<<256, 256, 0, stream>>>(X, Wg, counts, tok_list, inv_idx, inv_w, Xb);
    k_mlp_fused<<<NEXP * 80, 256, 0, stream>>>(Xb, w1t, b1, w2t, b2, counts, tok_list, yb);
    k_combine<<<2048, 256, 0, stream>>>(yb, inv_idx, inv_w, (float*)d_out);
}